// Round 10
// baseline (389.725 us; speedup 1.0000x reference)
//
#include <hip/hip_runtime.h>

// ---- problem constants ----
#define HWN 4096
#define CCH 512
#define NHEAD 8
#define DHD 64
#define NBATCH 2
#define QK_SCALE 0.35355339059327373f   // 64^-0.25
#define LOG2E    1.4426950408889634f

using floatx4 = __attribute__((ext_vector_type(4))) float;
using bf16x8  = __attribute__((ext_vector_type(8))) short;
using bf16x4  = __attribute__((ext_vector_type(4))) short;

__device__ __forceinline__ unsigned short f2b(float f) {
  union { float f; unsigned u; } x; x.f = f;
  unsigned r = x.u + 0x7FFFu + ((x.u >> 16) & 1u);
  return (unsigned short)(r >> 16);
}

__device__ __forceinline__ float b2f(unsigned short u) {
  union { unsigned u; float f; } x; x.u = ((unsigned)u) << 16;
  return x.f;
}

__device__ __forceinline__ float fast_exp2(float x) {
#if __has_builtin(__builtin_amdgcn_exp2f)
  return __builtin_amdgcn_exp2f(x);
#else
  return __expf(x * 0.69314718056f);
#endif
}

// pack bf16(lo),bf16(hi) from two floats in ONE v_perm_b32 (truncating round)
__device__ __forceinline__ unsigned pack_bf16_trunc(float lo, float hi) {
  return __builtin_amdgcn_perm(__float_as_uint(hi), __float_as_uint(lo), 0x07060302u);
}

// ---------------- 1. GroupNorm partial sums: grid (64 groups, 8 parts) ----------------
__global__ __launch_bounds__(256) void gn_stats(const float* __restrict__ x,
                                                float* __restrict__ stat) {
  int bg = blockIdx.x;
  const float4* p = (const float4*)(x + (size_t)bg * 65536) + blockIdx.y * 2048;
  float s = 0.f, ss = 0.f;
  for (int i = threadIdx.x; i < 2048; i += 256) {
    float4 v = p[i];
    s  += v.x + v.y + v.z + v.w;
    ss += v.x*v.x + v.y*v.y + v.z*v.z + v.w*v.w;
  }
  for (int off = 32; off; off >>= 1) {
    s  += __shfl_xor(s, off);
    ss += __shfl_xor(ss, off);
  }
  __shared__ float red[8];
  int w = threadIdx.x >> 6;
  if ((threadIdx.x & 63) == 0) { red[w] = s; red[4 + w] = ss; }
  __syncthreads();
  if (threadIdx.x == 0) {
    float S  = red[0] + red[1] + red[2] + red[3];
    float SS = red[4] + red[5] + red[6] + red[7];
    atomicAdd(&stat[bg], S);
    atomicAdd(&stat[64 + bg], SS);
  }
}

// ---------------- 2. weight prep: fp32 -> bf16, fold SCALE (and log2e into q) ----------------
__global__ __launch_bounds__(256) void prep_w(
    const float* __restrict__ wq, const float* __restrict__ wk,
    const float* __restrict__ wv, const float* __restrict__ wp,
    const float* __restrict__ bq, const float* __restrict__ bk,
    const float* __restrict__ bv,
    unsigned short* __restrict__ Wqkv, unsigned short* __restrict__ Wp,
    float* __restrict__ bqkv) {
  int i = blockIdx.x * 256 + threadIdx.x;
  if (i < 786432) {                       // Wqkv: rows 0-511 q, 512-1023 k, 1024-1535 v
    int row = i >> 9;
    float v;
    if (row < 512)       v = wq[i] * (QK_SCALE * LOG2E);
    else if (row < 1024) v = wk[i - 262144] * QK_SCALE;
    else                 v = wv[i - 524288];
    Wqkv[i] = f2b(v);
  } else if (i < 1048576) {
    Wp[i - 786432] = f2b(wp[i - 786432]);
  } else if (i < 1050112) {
    int j = i - 1048576;
    float v = (j < 512) ? bq[j] * (QK_SCALE * LOG2E)
            : (j < 1024) ? bk[j - 512] * QK_SCALE
            : bv[j - 1024];
    bqkv[j] = v;
  }
}

// ---------------- 3. normalize + transpose to t[(b*4096+p)*512 + c] bf16 ----------------
__global__ __launch_bounds__(256) void gn_apply(
    const float* __restrict__ x, const float* __restrict__ stat,
    const float* __restrict__ gnw, const float* __restrict__ gnb,
    unsigned short* __restrict__ t) {
  int pt = blockIdx.x & 63;
  int ct = (blockIdx.x >> 6) & 7;
  int b  = blockIdx.x >> 9;
  int c0 = ct * 64, p0 = pt * 64;
  __shared__ float tile[64][68];          // pad 68: bank shift 4/row, float4-aligned
  int tid = threadIdx.x;
  for (int pp = 0; pp < 4; ++pp) {
    int f = (pp * 256 + tid) * 4;
    int cl = f >> 6, pl = f & 63;
    int c = c0 + cl;
    float4 v = *(const float4*)(x + ((size_t)(b * 512 + c)) * 4096 + p0 + pl);
    int g = c >> 4;
    float S    = stat[b * 32 + g];
    float SS   = stat[64 + b * 32 + g];
    float mean = S * (1.f / 65536.f);
    float var  = SS * (1.f / 65536.f) - mean * mean;
    float rstd = rsqrtf(var + 1e-5f);
    float w  = gnw[c] * rstd;
    float bb = gnb[c] - mean * w;
    tile[cl][pl + 0] = v.x * w + bb;
    tile[cl][pl + 1] = v.y * w + bb;
    tile[cl][pl + 2] = v.z * w + bb;
    tile[cl][pl + 3] = v.w * w + bb;
  }
  __syncthreads();
  for (int pp = 0; pp < 2; ++pp) {
    int f = (pp * 256 + tid) * 8;
    int pl = f >> 6, cl = f & 63;
    unsigned short u[8];
#pragma unroll
    for (int j = 0; j < 8; ++j) u[j] = f2b(tile[cl + j][pl]);
    *(uint4*)(t + ((size_t)(b * 4096 + p0 + pl)) * 512 + c0 + cl) = *(uint4*)u;
  }
}

// ---------------- 4. QKV GEMM ----------------
// q/k: [(bh*4096+p)*64+d] bf16 ; v: TRANSPOSED [bh][d][4096] bf16
__global__ __launch_bounds__(256) void gemm_qkv(
    const unsigned short* __restrict__ t, const unsigned short* __restrict__ Wqkv,
    const float* __restrict__ bqkv,
    unsigned short* __restrict__ qo, unsigned short* __restrict__ ko,
    unsigned short* __restrict__ vo) {
  int M0 = blockIdx.x * 64;   // pixel 0..8128
  int N0 = blockIdx.y * 64;   // outch 0..1472
  __shared__ unsigned short At[64][72];
  __shared__ unsigned short Bt[64][72];
  int tid = threadIdx.x, w = tid >> 6, l = tid & 63;
  int quad = l >> 4, m16 = l & 15;
  floatx4 acc[4] = {};
  for (int k0 = 0; k0 < 512; k0 += 64) {
    __syncthreads();
#pragma unroll
    for (int pp = 0; pp < 2; ++pp) {
      int f = (pp * 256 + tid) * 8;
      int r = f >> 6, c = f & 63;
      *(uint4*)&At[r][c] = *(const uint4*)(t    + (size_t)(M0 + r) * 512 + k0 + c);
      *(uint4*)&Bt[r][c] = *(const uint4*)(Wqkv + (size_t)(N0 + r) * 512 + k0 + c);
    }
    __syncthreads();
    bf16x8 af0 = *(const bf16x8*)&At[w * 16 + m16][quad * 8];
    bf16x8 af1 = *(const bf16x8*)&At[w * 16 + m16][32 + quad * 8];
#pragma unroll
    for (int nt = 0; nt < 4; ++nt) {
      bf16x8 b0 = *(const bf16x8*)&Bt[nt * 16 + m16][quad * 8];
      bf16x8 b1 = *(const bf16x8*)&Bt[nt * 16 + m16][32 + quad * 8];
      acc[nt] = __builtin_amdgcn_mfma_f32_16x16x32_bf16(af0, b0, acc[nt], 0, 0, 0);
      acc[nt] = __builtin_amdgcn_mfma_f32_16x16x32_bf16(af1, b1, acc[nt], 0, 0, 0);
    }
  }
  int which = N0 >> 9;
  int head  = (N0 & 511) >> 6;
  if (which == 2) {
    // V: transpose 64x64 tile through LDS, store [bh][d][4096] coalesced
    __syncthreads();
#pragma unroll
    for (int nt = 0; nt < 4; ++nt) {
      int d = nt * 16 + m16;
      float bias = bqkv[N0 + d];
#pragma unroll
      for (int r = 0; r < 4; ++r)
        At[d][w * 16 + quad * 4 + r] = f2b(acc[nt][r] + bias);
    }
    __syncthreads();
    int bb = M0 >> 12, p0 = M0 & 4095;
    unsigned short* dst = vo + ((size_t)(bb * 8 + head) * 64) * 4096;
#pragma unroll
    for (int pp = 0; pp < 2; ++pp) {
      int f = (pp * 256 + tid) * 8;
      int d = f >> 6, pl = f & 63;
      *(uint4*)(dst + (size_t)d * 4096 + p0 + pl) = *(uint4*)&At[d][pl];
    }
  } else {
    unsigned short* dst = (which == 0) ? qo : ko;
#pragma unroll
    for (int nt = 0; nt < 4; ++nt) {
      int n = N0 + nt * 16 + m16;
      float bias = bqkv[n];
      int d = n & 63;
#pragma unroll
      for (int r = 0; r < 4; ++r) {
        int m = M0 + w * 16 + quad * 4 + r;   // pixel 0..8191
        int b = m >> 12, p = m & 4095;
        dst[(((size_t)(b * 8 + head) * 4096 + p) << 6) + d] = f2b(acc[nt][r] + bias);
      }
    }
  }
}

// ---------------- 5. flash attention, kv-split ----------------
// R9 body (2-stream 32 q/wave, K-tile=128, key-permuted K=32 PV, ones-MFMA l)
// with the key range SPLIT 2 ways across blocks: grid (32 qt, 16 bh, 2 ks) =
// 1024 blocks -> 4 blocks/CU = 16 waves/CU (R9 was grid-limited to 2/CU,
// which cancelled the LDS dedup win). Each block does 16 rounds over its
// 2048 keys and writes a NORMALIZED bf16 partial O + per-query (m,l); a tiny
// LSE merge kernel combines the two splits. Partials live in d_out (exactly
// fits, fully overwritten by gemm_out later); (m,l) in the dead t buffer.
__global__ __launch_bounds__(256, 4) void attn(
    const unsigned short* __restrict__ q, const unsigned short* __restrict__ k,
    const unsigned short* __restrict__ vt,
    unsigned short* __restrict__ pO, float* __restrict__ mlbuf) {
  int qt = blockIdx.x;           // 0..31  (128 queries)
  int bh = blockIdx.y;           // 0..15
  int ks = blockIdx.z;           // 0..1   (2048-key half)
  __shared__ unsigned short Kt[128][72];    // [key][d]   18.4 KB
  __shared__ unsigned short Vt[64][136];    // [d][key]   17.4 KB
  int tid = threadIdx.x, w = tid >> 6, l = tid & 63;
  int quad = l >> 4, m16 = l & 15;
  const size_t base = (size_t)bh * HWN * DHD;
  const int key0 = ks * 2048;
  int krow_base = ((m16 >> 2) * 8) + (m16 & 3);   // key-permutation base

  // Q frags for streams A (queries qt*128+w*32+m16) and B (+16)
  bf16x8 qfA0, qfA1, qfB0, qfB1;
  {
    int qrow = qt * 128 + w * 32 + m16;
    const unsigned short* qp = q + base + (size_t)qrow * 64 + quad * 8;
    qfA0 = *(const bf16x8*)qp;
    qfA1 = *(const bf16x8*)(qp + 32);
    qfB0 = *(const bf16x8*)(qp + 16 * 64);
    qfB1 = *(const bf16x8*)(qp + 16 * 64 + 32);
  }
  bf16x8 ones;
#pragma unroll
  for (int z = 0; z < 8; ++z) ones[z] = (short)0x3F80;   // 1.0 bf16

  floatx4 accOA[4] = {}, accOB[4] = {};
  floatx4 accLA = {}, accLB = {};
  float mrowA = -1e30f, mrowB = -1e30f;

  for (int kt = 0; kt < 16; ++kt) {
    __syncthreads();
#pragma unroll
    for (int pp = 0; pp < 4; ++pp) {
      int f = (pp * 256 + tid) * 8;
      int rk = f >> 6, ck = f & 63;       // K: 128 rows x 64
      *(uint4*)&Kt[rk][ck] = *(const uint4*)(k + base + (size_t)(key0 + kt * 128 + rk) * 64 + ck);
      int rv = f >> 7, cv = f & 127;      // V: 64 rows x 128
      *(uint4*)&Vt[rv][cv] = *(const uint4*)(vt + base + (size_t)rv * 4096 + key0 + kt * 128 + cv);
    }
    __syncthreads();
    // S^T = K * Q^T, permuted keys; each kf read feeds BOTH streams.
    floatx4 sA[8], sB[8];
#pragma unroll
    for (int nt = 0; nt < 4; ++nt)
#pragma unroll
      for (int hh = 0; hh < 2; ++hh) {
        int row = nt * 32 + hh * 4 + krow_base;
        bf16x8 kf0 = *(const bf16x8*)&Kt[row][quad * 8];
        bf16x8 kf1 = *(const bf16x8*)&Kt[row][32 + quad * 8];
        floatx4 zA = {}, zB = {};
        zA = __builtin_amdgcn_mfma_f32_16x16x32_bf16(kf0, qfA0, zA, 0, 0, 0);
        sA[nt * 2 + hh] = __builtin_amdgcn_mfma_f32_16x16x32_bf16(kf1, qfA1, zA, 0, 0, 0);
        zB = __builtin_amdgcn_mfma_f32_16x16x32_bf16(kf0, qfB0, zB, 0, 0, 0);
        sB[nt * 2 + hh] = __builtin_amdgcn_mfma_f32_16x16x32_bf16(kf1, qfB1, zB, 0, 0, 0);
      }
    // online softmax (both streams)
    float mxA = sA[0][0], mxB = sB[0][0];
#pragma unroll
    for (int nt = 0; nt < 8; ++nt)
#pragma unroll
      for (int i = 0; i < 4; ++i) {
        mxA = fmaxf(mxA, sA[nt][i]);
        mxB = fmaxf(mxB, sB[nt][i]);
      }
    mxA = fmaxf(mxA, __shfl_xor(mxA, 16));
    mxA = fmaxf(mxA, __shfl_xor(mxA, 32));
    mxB = fmaxf(mxB, __shfl_xor(mxB, 16));
    mxB = fmaxf(mxB, __shfl_xor(mxB, 32));
    bool grew = (mxA > mrowA) || (mxB > mrowB);
    float mnA = fmaxf(mrowA, mxA);
    float mnB = fmaxf(mrowB, mxB);
#pragma unroll
    for (int nt = 0; nt < 8; ++nt)
#pragma unroll
      for (int i = 0; i < 4; ++i) {
        sA[nt][i] = fast_exp2(sA[nt][i] - mnA);
        sB[nt][i] = fast_exp2(sB[nt][i] - mnB);
      }
    if (__ballot(grew)) {
      float aA = fast_exp2(mrowA - mnA);
      float aB = fast_exp2(mrowB - mnB);
      float a0 = __shfl(aA, quad * 4 + 0), b0 = __shfl(aB, quad * 4 + 0);
      float a1 = __shfl(aA, quad * 4 + 1), b1 = __shfl(aB, quad * 4 + 1);
      float a2 = __shfl(aA, quad * 4 + 2), b2 = __shfl(aB, quad * 4 + 2);
      float a3 = __shfl(aA, quad * 4 + 3), b3 = __shfl(aB, quad * 4 + 3);
#pragma unroll
      for (int dt = 0; dt < 4; ++dt) {
        accOA[dt][0] *= a0; accOA[dt][1] *= a1; accOA[dt][2] *= a2; accOA[dt][3] *= a3;
        accOB[dt][0] *= b0; accOB[dt][1] *= b1; accOB[dt][2] *= b2; accOB[dt][3] *= b3;
      }
      accLA[0] *= a0; accLA[1] *= a1; accLA[2] *= a2; accLA[3] *= a3;
      accLB[0] *= b0; accLB[1] *= b1; accLB[2] *= b2; accLB[3] *= b3;
    }
    mrowA = mnA; mrowB = mnB;
    // P -> bf16 A-frags (K=32)
    bf16x8 pfA[4], pfB[4];
#pragma unroll
    for (int nt = 0; nt < 4; ++nt) {
      union { unsigned u[4]; bf16x8 v; } pa, pb;
      pa.u[0] = pack_bf16_trunc(sA[nt * 2][0],     sA[nt * 2][1]);
      pa.u[1] = pack_bf16_trunc(sA[nt * 2][2],     sA[nt * 2][3]);
      pa.u[2] = pack_bf16_trunc(sA[nt * 2 + 1][0], sA[nt * 2 + 1][1]);
      pa.u[3] = pack_bf16_trunc(sA[nt * 2 + 1][2], sA[nt * 2 + 1][3]);
      pfA[nt] = pa.v;
      pb.u[0] = pack_bf16_trunc(sB[nt * 2][0],     sB[nt * 2][1]);
      pb.u[1] = pack_bf16_trunc(sB[nt * 2][2],     sB[nt * 2][3]);
      pb.u[2] = pack_bf16_trunc(sB[nt * 2 + 1][0], sB[nt * 2 + 1][1]);
      pb.u[3] = pack_bf16_trunc(sB[nt * 2 + 1][2], sB[nt * 2 + 1][3]);
      pfB[nt] = pb.v;
    }
    // O += P*V (K=32): each vf read feeds BOTH streams
#pragma unroll
    for (int dt = 0; dt < 4; ++dt) {
#pragma unroll
      for (int nt = 0; nt < 4; ++nt) {
        bf16x8 vf = *(const bf16x8*)&Vt[dt * 16 + m16][nt * 32 + quad * 8];
        accOA[dt] = __builtin_amdgcn_mfma_f32_16x16x32_bf16(pfA[nt], vf, accOA[dt], 0, 0, 0);
        accOB[dt] = __builtin_amdgcn_mfma_f32_16x16x32_bf16(pfB[nt], vf, accOB[dt], 0, 0, 0);
      }
    }
#pragma unroll
    for (int nt = 0; nt < 4; ++nt) {
      accLA = __builtin_amdgcn_mfma_f32_16x16x32_bf16(pfA[nt], ones, accLA, 0, 0, 0);
      accLB = __builtin_amdgcn_mfma_f32_16x16x32_bf16(pfB[nt], ones, accLB, 0, 0, 0);
    }
  }
  // ---- epilogue: normalized bf16 partial O + (m,l) per query ----
  const size_t prow = (size_t)(ks * 16 + bh) * 4096;
  float lA0 = 1.f / accLA[0], lA1 = 1.f / accLA[1], lA2 = 1.f / accLA[2], lA3 = 1.f / accLA[3];
  float lB0 = 1.f / accLB[0], lB1 = 1.f / accLB[1], lB2 = 1.f / accLB[2], lB3 = 1.f / accLB[3];
#pragma unroll
  for (int dt = 0; dt < 4; ++dt) {
    int d = dt * 16 + m16;
    int qrowA = qt * 128 + w * 32 + quad * 4;
    size_t rb = (prow + qrowA) * 64 + d;
    pO[rb]        = f2b(accOA[dt][0] * lA0);
    pO[rb + 64]   = f2b(accOA[dt][1] * lA1);
    pO[rb + 128]  = f2b(accOA[dt][2] * lA2);
    pO[rb + 192]  = f2b(accOA[dt][3] * lA3);
    size_t rb2 = rb + 16 * 64;
    pO[rb2]       = f2b(accOB[dt][0] * lB0);
    pO[rb2 + 64]  = f2b(accOB[dt][1] * lB1);
    pO[rb2 + 128] = f2b(accOB[dt][2] * lB2);
    pO[rb2 + 192] = f2b(accOB[dt][3] * lB3);
  }
  if (m16 < 4) {
    // lane (quad, m16): stats for query w*32 + quad*4 + m16 (stream A) / +16 (B)
    float mvA = __shfl(mrowA, quad * 4 + m16);
    float mvB = __shfl(mrowB, quad * 4 + m16);
    float lvA = (m16 == 0) ? accLA[0] : (m16 == 1) ? accLA[1] : (m16 == 2) ? accLA[2] : accLA[3];
    float lvB = (m16 == 0) ? accLB[0] : (m16 == 1) ? accLB[1] : (m16 == 2) ? accLB[2] : accLB[3];
    int qrow = qt * 128 + w * 32 + quad * 4 + m16;
    float2* mlp = (float2*)mlbuf;
    float2 va; va.x = mvA; va.y = lvA;
    float2 vb; vb.x = mvB; vb.y = lvB;
    mlp[prow + qrow]      = va;
    mlp[prow + qrow + 16] = vb;
  }
}

// ---------------- 5b. LSE merge of the two kv-splits ----------------
__global__ __launch_bounds__(256) void attn_merge(
    const unsigned short* __restrict__ pO, const float* __restrict__ mlbuf,
    unsigned short* __restrict__ ob) {
  int r = blockIdx.x * 64 + (threadIdx.x >> 2);   // row over 16 bh x 4096 q
  int dseg = (threadIdx.x & 3) * 16;
  int bh = r >> 12, qq = r & 4095;
  int b = bh >> 3, h = bh & 7;
  const float2* mlp = (const float2*)mlbuf;
  float2 ml0 = mlp[r];
  float2 ml1 = mlp[65536 + r];
  float ms = fmaxf(ml0.x, ml1.x);
  float s0 = fast_exp2(ml0.x - ms) * ml0.y;
  float s1 = fast_exp2(ml1.x - ms) * ml1.y;
  float inv = 1.f / (s0 + s1);
  float w0 = s0 * inv, w1 = s1 * inv;
  const unsigned short* p0 = pO + ((size_t)r * 64 + dseg);
  const unsigned short* p1 = p0 + (size_t)65536 * 64;
  uint4 u0a = *(const uint4*)p0, u0b = *(const uint4*)(p0 + 8);
  uint4 u1a = *(const uint4*)p1, u1b = *(const uint4*)(p1 + 8);
  const unsigned short* a0 = (const unsigned short*)&u0a;
  const unsigned short* a1 = (const unsigned short*)&u1a;
  const unsigned short* b0p = (const unsigned short*)&u0b;
  const unsigned short* b1p = (const unsigned short*)&u1b;
  unsigned short u[16];
#pragma unroll
  for (int z = 0; z < 8; ++z) {
    u[z]     = f2b(w0 * b2f(a0[z])  + w1 * b2f(a1[z]));
    u[8 + z] = f2b(w0 * b2f(b0p[z]) + w1 * b2f(b1p[z]));
  }
  unsigned short* op = ob + ((size_t)(b * 4096 + qq)) * 512 + h * 64 + dseg;
  *(uint4*)op       = *(uint4*)u;
  *(uint4*)(op + 8) = *(uint4*)(u + 8);
}

// ---------------- 6. out-proj + bias + residual, coalesced fp32 store ----------------
__global__ __launch_bounds__(256) void gemm_out(
    const unsigned short* __restrict__ o, const unsigned short* __restrict__ Wp,
    const float* __restrict__ bp, const float* __restrict__ x,
    float* __restrict__ out) {
  int C0 = blockIdx.x * 64, P0 = blockIdx.y * 64, b = blockIdx.z;
  __shared__ unsigned short At[64][72];   // Wp rows (channel)
  __shared__ unsigned short Bt[64][72];   // o rows (pixel)
  int tid = threadIdx.x, w = tid >> 6, l = tid & 63;
  int quad = l >> 4, m16 = l & 15;
  floatx4 acc[4] = {};
  for (int k0 = 0; k0 < 512; k0 += 64) {
    __syncthreads();
#pragma unroll
    for (int pp = 0; pp < 2; ++pp) {
      int f = (pp * 256 + tid) * 8;
      int r = f >> 6, c = f & 63;
      *(uint4*)&At[r][c] = *(const uint4*)(Wp + (size_t)(C0 + r) * 512 + k0 + c);
      *(uint4*)&Bt[r][c] = *(const uint4*)(o + ((size_t)(b * 4096 + P0 + r)) * 512 + k0 + c);
    }
    __syncthreads();
    bf16x8 af0 = *(const bf16x8*)&At[w * 16 + m16][quad * 8];
    bf16x8 af1 = *(const bf16x8*)&At[w * 16 + m16][32 + quad * 8];
#pragma unroll
    for (int nt = 0; nt < 4; ++nt) {
      bf16x8 b0 = *(const bf16x8*)&Bt[nt * 16 + m16][quad * 8];
      bf16x8 b1 = *(const bf16x8*)&Bt[nt * 16 + m16][32 + quad * 8];
      acc[nt] = __builtin_amdgcn_mfma_f32_16x16x32_bf16(af0, b0, acc[nt], 0, 0, 0);
      acc[nt] = __builtin_amdgcn_mfma_f32_16x16x32_bf16(af1, b1, acc[nt], 0, 0, 0);
    }
  }
#pragma unroll
  for (int r = 0; r < 4; ++r) {
    int c = C0 + w * 16 + quad * 4 + r;
    float bias = bp[c];
#pragma unroll
    for (int nt = 0; nt < 4; ++nt) {
      int p = P0 + nt * 16 + m16;
      size_t idx = ((size_t)(b * 512 + c)) * 4096 + p;
      out[idx] = acc[nt][r] + bias + x[idx];
    }
  }
}

extern "C" void kernel_launch(void* const* d_in, const int* in_sizes, int n_in,
                              void* d_out, int out_size, void* d_ws, size_t ws_size,
                              hipStream_t stream) {
  const float* x   = (const float*)d_in[0];
  const float* gnw = (const float*)d_in[1];
  const float* gnb = (const float*)d_in[2];
  const float* wq  = (const float*)d_in[3];
  const float* bq  = (const float*)d_in[4];
  const float* wk  = (const float*)d_in[5];
  const float* bk  = (const float*)d_in[6];
  const float* wv  = (const float*)d_in[7];
  const float* bv  = (const float*)d_in[8];
  const float* wp  = (const float*)d_in[9];
  const float* bp  = (const float*)d_in[10];
  float* out = (float*)d_out;

  char* ws = (char*)d_ws;
  float* stat          = (float*)ws;          ws += 1024;
  float* bqkv          = (float*)ws;          ws += 8192;
  unsigned short* Wqkv = (unsigned short*)ws; ws += (size_t)1536 * 512 * 2;
  unsigned short* Wp   = (unsigned short*)ws; ws += (size_t)512 * 512 * 2;
  unsigned short* t    = (unsigned short*)ws; ws += (size_t)8192 * 512 * 2;
  unsigned short* qb   = (unsigned short*)ws; ws += (size_t)8192 * 512 * 2;
  unsigned short* kb   = (unsigned short*)ws; ws += (size_t)8192 * 512 * 2;
  unsigned short* vb   = (unsigned short*)ws; ws += (size_t)8192 * 512 * 2;  // [16][64][4096]
  unsigned short* ob   = (unsigned short*)ws; ws += (size_t)8192 * 512 * 2;

  // attn partials: d_out (16.78 MB, exactly 2x16x4096x64 bf16; fully
  // overwritten by gemm_out). (m,l) stats: reuse t (dead after gemm_qkv).
  unsigned short* pO  = (unsigned short*)d_out;
  float* mlbuf        = (float*)t;

  hipMemsetAsync(stat, 0, 512, stream);
  dim3 g0(64, 8);
  gn_stats<<<g0, 256, 0, stream>>>(x, stat);
  prep_w<<<4103, 256, 0, stream>>>(wq, wk, wv, wp, bq, bk, bv, Wqkv, Wp, bqkv);
  gn_apply<<<1024, 256, 0, stream>>>(x, stat, gnw, gnb, t);
  dim3 g1(128, 24);
  gemm_qkv<<<g1, 256, 0, stream>>>(t, Wqkv, bqkv, qb, kb, vb);
  dim3 g2(32, 16, 2);
  attn<<<g2, 256, 0, stream>>>(qb, kb, vb, pO, mlbuf);
  attn_merge<<<1024, 256, 0, stream>>>(pO, mlbuf, ob);
  dim3 g3(8, 64, 2);
  gemm_out<<<g3, 256, 0, stream>>>(ob, Wp, bp, x, out);
}

// Round 11
// 254.973 us; speedup vs baseline: 1.5285x; 1.5285x over previous
//
#include <hip/hip_runtime.h>

// ---- problem constants ----
#define HWN 4096
#define CCH 512
#define NHEAD 8
#define DHD 64
#define NBATCH 2
#define QK_SCALE 0.35355339059327373f   // 64^-0.25
#define LOG2E    1.4426950408889634f

using floatx4 = __attribute__((ext_vector_type(4))) float;
using bf16x8  = __attribute__((ext_vector_type(8))) short;
using bf16x4  = __attribute__((ext_vector_type(4))) short;

__device__ __forceinline__ unsigned short f2b(float f) {
  union { float f; unsigned u; } x; x.f = f;
  unsigned r = x.u + 0x7FFFu + ((x.u >> 16) & 1u);
  return (unsigned short)(r >> 16);
}

__device__ __forceinline__ float b2f(unsigned short u) {
  union { unsigned u; float f; } x; x.u = ((unsigned)u) << 16;
  return x.f;
}

__device__ __forceinline__ float fast_exp2(float x) {
#if __has_builtin(__builtin_amdgcn_exp2f)
  return __builtin_amdgcn_exp2f(x);
#else
  return __expf(x * 0.69314718056f);
#endif
}

// pack bf16(lo),bf16(hi) from two floats in ONE v_perm_b32 (truncating round)
__device__ __forceinline__ unsigned pack_bf16_trunc(float lo, float hi) {
  return __builtin_amdgcn_perm(__float_as_uint(hi), __float_as_uint(lo), 0x07060302u);
}

// ---------------- 1. GroupNorm partial sums: grid (64 groups, 8 parts) ----------------
__global__ __launch_bounds__(256) void gn_stats(const float* __restrict__ x,
                                                float* __restrict__ stat) {
  int bg = blockIdx.x;
  const float4* p = (const float4*)(x + (size_t)bg * 65536) + blockIdx.y * 2048;
  float s = 0.f, ss = 0.f;
  for (int i = threadIdx.x; i < 2048; i += 256) {
    float4 v = p[i];
    s  += v.x + v.y + v.z + v.w;
    ss += v.x*v.x + v.y*v.y + v.z*v.z + v.w*v.w;
  }
  for (int off = 32; off; off >>= 1) {
    s  += __shfl_xor(s, off);
    ss += __shfl_xor(ss, off);
  }
  __shared__ float red[8];
  int w = threadIdx.x >> 6;
  if ((threadIdx.x & 63) == 0) { red[w] = s; red[4 + w] = ss; }
  __syncthreads();
  if (threadIdx.x == 0) {
    float S  = red[0] + red[1] + red[2] + red[3];
    float SS = red[4] + red[5] + red[6] + red[7];
    atomicAdd(&stat[bg], S);
    atomicAdd(&stat[64 + bg], SS);
  }
}

// ---------------- 2. weight prep: fp32 -> bf16, fold SCALE (and log2e into q) ----------------
__global__ __launch_bounds__(256) void prep_w(
    const float* __restrict__ wq, const float* __restrict__ wk,
    const float* __restrict__ wv, const float* __restrict__ wp,
    const float* __restrict__ bq, const float* __restrict__ bk,
    const float* __restrict__ bv,
    unsigned short* __restrict__ Wqkv, unsigned short* __restrict__ Wp,
    float* __restrict__ bqkv) {
  int i = blockIdx.x * 256 + threadIdx.x;
  if (i < 786432) {                       // Wqkv: rows 0-511 q, 512-1023 k, 1024-1535 v
    int row = i >> 9;
    float v;
    if (row < 512)       v = wq[i] * (QK_SCALE * LOG2E);
    else if (row < 1024) v = wk[i - 262144] * QK_SCALE;
    else                 v = wv[i - 524288];
    Wqkv[i] = f2b(v);
  } else if (i < 1048576) {
    Wp[i - 786432] = f2b(wp[i - 786432]);
  } else if (i < 1050112) {
    int j = i - 1048576;
    float v = (j < 512) ? bq[j] * (QK_SCALE * LOG2E)
            : (j < 1024) ? bk[j - 512] * QK_SCALE
            : bv[j - 1024];
    bqkv[j] = v;
  }
}

// ---------------- 3. normalize + transpose to t[(b*4096+p)*512 + c] bf16 ----------------
__global__ __launch_bounds__(256) void gn_apply(
    const float* __restrict__ x, const float* __restrict__ stat,
    const float* __restrict__ gnw, const float* __restrict__ gnb,
    unsigned short* __restrict__ t) {
  int pt = blockIdx.x & 63;
  int ct = (blockIdx.x >> 6) & 7;
  int b  = blockIdx.x >> 9;
  int c0 = ct * 64, p0 = pt * 64;
  __shared__ float tile[64][68];          // pad 68: bank shift 4/row, float4-aligned
  int tid = threadIdx.x;
  for (int pp = 0; pp < 4; ++pp) {
    int f = (pp * 256 + tid) * 4;
    int cl = f >> 6, pl = f & 63;
    int c = c0 + cl;
    float4 v = *(const float4*)(x + ((size_t)(b * 512 + c)) * 4096 + p0 + pl);
    int g = c >> 4;
    float S    = stat[b * 32 + g];
    float SS   = stat[64 + b * 32 + g];
    float mean = S * (1.f / 65536.f);
    float var  = SS * (1.f / 65536.f) - mean * mean;
    float rstd = rsqrtf(var + 1e-5f);
    float w  = gnw[c] * rstd;
    float bb = gnb[c] - mean * w;
    tile[cl][pl + 0] = v.x * w + bb;
    tile[cl][pl + 1] = v.y * w + bb;
    tile[cl][pl + 2] = v.z * w + bb;
    tile[cl][pl + 3] = v.w * w + bb;
  }
  __syncthreads();
  for (int pp = 0; pp < 2; ++pp) {
    int f = (pp * 256 + tid) * 8;
    int pl = f >> 6, cl = f & 63;
    unsigned short u[8];
#pragma unroll
    for (int j = 0; j < 8; ++j) u[j] = f2b(tile[cl + j][pl]);
    *(uint4*)(t + ((size_t)(b * 4096 + p0 + pl)) * 512 + c0 + cl) = *(uint4*)u;
  }
}

// ---------------- 4. QKV GEMM ----------------
// q: [(bh*4096+p)*64+d] bf16 ; v: TRANSPOSED [bh][d][4096] bf16 ;
// K: FRAG-MAJOR Kp[bh][kb(32)][ig(8)][half(2)][lane(64)x8] bf16 — each 1 KB
// chunk is exactly one wave-wide A-frag load for attn (lane-contiguous 16 B).
// Chunk semantics: lane l (quad=l>>4, m16=l&15), byte j -> K[key = kb*128 +
// (ig>>1)*32 + (ig&1)*4 + (m16>>2)*8 + (m16&3)][d = half*32 + quad*8 + j/2].
__global__ __launch_bounds__(256) void gemm_qkv(
    const unsigned short* __restrict__ t, const unsigned short* __restrict__ Wqkv,
    const float* __restrict__ bqkv,
    unsigned short* __restrict__ qo, unsigned short* __restrict__ Kp,
    unsigned short* __restrict__ vo) {
  int M0 = blockIdx.x * 64;   // pixel 0..8128
  int N0 = blockIdx.y * 64;   // outch 0..1472
  __shared__ unsigned short At[64][72];
  __shared__ unsigned short Bt[64][72];
  int tid = threadIdx.x, w = tid >> 6, l = tid & 63;
  int quad = l >> 4, m16 = l & 15;
  floatx4 acc[4] = {};
  for (int k0 = 0; k0 < 512; k0 += 64) {
    __syncthreads();
#pragma unroll
    for (int pp = 0; pp < 2; ++pp) {
      int f = (pp * 256 + tid) * 8;
      int r = f >> 6, c = f & 63;
      *(uint4*)&At[r][c] = *(const uint4*)(t    + (size_t)(M0 + r) * 512 + k0 + c);
      *(uint4*)&Bt[r][c] = *(const uint4*)(Wqkv + (size_t)(N0 + r) * 512 + k0 + c);
    }
    __syncthreads();
    bf16x8 af0 = *(const bf16x8*)&At[w * 16 + m16][quad * 8];
    bf16x8 af1 = *(const bf16x8*)&At[w * 16 + m16][32 + quad * 8];
#pragma unroll
    for (int nt = 0; nt < 4; ++nt) {
      bf16x8 b0 = *(const bf16x8*)&Bt[nt * 16 + m16][quad * 8];
      bf16x8 b1 = *(const bf16x8*)&Bt[nt * 16 + m16][32 + quad * 8];
      acc[nt] = __builtin_amdgcn_mfma_f32_16x16x32_bf16(af0, b0, acc[nt], 0, 0, 0);
      acc[nt] = __builtin_amdgcn_mfma_f32_16x16x32_bf16(af1, b1, acc[nt], 0, 0, 0);
    }
  }
  int which = N0 >> 9;
  int head  = (N0 & 511) >> 6;
  if (which == 2) {
    // V: transpose 64x64 tile through LDS, store [bh][d][4096] coalesced
    __syncthreads();
#pragma unroll
    for (int nt = 0; nt < 4; ++nt) {
      int d = nt * 16 + m16;
      float bias = bqkv[N0 + d];
#pragma unroll
      for (int r = 0; r < 4; ++r)
        At[d][w * 16 + quad * 4 + r] = f2b(acc[nt][r] + bias);
    }
    __syncthreads();
    int bb = M0 >> 12, p0 = M0 & 4095;
    unsigned short* dst = vo + ((size_t)(bb * 8 + head) * 64) * 4096;
#pragma unroll
    for (int pp = 0; pp < 2; ++pp) {
      int f = (pp * 256 + tid) * 8;
      int d = f >> 6, pl = f & 63;
      *(uint4*)(dst + (size_t)d * 4096 + p0 + pl) = *(uint4*)&At[d][pl];
    }
  } else if (which == 1) {
    // K: repack to frag-major Kp. Stage [key_local][d] in LDS, read back in
    // frag order, store lane-contiguous 1 KB chunks.
    __syncthreads();
#pragma unroll
    for (int nt = 0; nt < 4; ++nt) {
      float bias = bqkv[N0 + nt * 16 + m16];
#pragma unroll
      for (int r = 0; r < 4; ++r)
        At[w * 16 + quad * 4 + r][nt * 16 + m16] = f2b(acc[nt][r] + bias);
    }
    __syncthreads();
    int bb = M0 >> 12, p = M0 & 4095;
    int kb = p >> 7, halfblk = (p >> 6) & 1;
    int ig = halfblk * 4 + w;             // ig = nt_g*2+hh, nt_g=halfblk*2+(w>>1), hh=w&1
    int ntl = w >> 1, hh = w & 1;
    int row = ntl * 32 + hh * 4 + ((m16 >> 2) << 3) + (m16 & 3);  // local key row
    size_t dstb = (((size_t)(bb * 8 + head) * 32 + kb) * 8 + ig) * 1024;
#pragma unroll
    for (int pp = 0; pp < 2; ++pp)
      *(uint4*)(Kp + dstb + pp * 512 + l * 8) = *(uint4*)&At[row][pp * 32 + quad * 8];
  } else {
    // Q: row-major per-head
#pragma unroll
    for (int nt = 0; nt < 4; ++nt) {
      int n = N0 + nt * 16 + m16;
      float bias = bqkv[n];
      int d = n & 63;
#pragma unroll
      for (int r = 0; r < 4; ++r) {
        int m = M0 + w * 16 + quad * 4 + r;   // pixel 0..8191
        int b = m >> 12, pp2 = m & 4095;
        qo[(((size_t)(b * 8 + head) * 4096 + pp2) << 6) + d] = f2b(acc[nt][r] + bias);
      }
    }
  }
}

// ---------------- 5. flash attention, kv-split, K-frags from global ----------------
// 1-stream R8 body (56 VGPR proven, no spill) + kv-split x2 (grid 2048) +
// K A-frags loaded directly from frag-major Kp (lane-contiguous 1 KB loads,
// L1-resident: 16 KB K/round, 4-wave redundancy becomes L1 hits). Only V is
// LDS-staged: LDS ops/wave*round drop 40 -> 20 (the R8 floor), LDS 17.8 KB.
__global__ __launch_bounds__(256, 4) void attn(
    const unsigned short* __restrict__ q, const unsigned short* __restrict__ Kp,
    const unsigned short* __restrict__ vt,
    unsigned short* __restrict__ pO, float* __restrict__ mlbuf) {
  int qt = blockIdx.x;           // 0..63  (64-query tile)
  int bh = blockIdx.y;           // 0..15
  int ks = blockIdx.z;           // 0..1   (2048-key half)
  __shared__ unsigned short Vt[64][136];    // [d][key]   17.4 KB
  int tid = threadIdx.x, w = tid >> 6, l = tid & 63;
  int quad = l >> 4, m16 = l & 15;
  const size_t vbase = (size_t)bh * HWN * DHD;
  const int key0 = ks * 2048;

  bf16x8 qf0, qf1;   // Q[qrow][quad*8+j] -> B-frag of K=32 mfma
  {
    int qrow = qt * 64 + w * 16 + m16;
    const unsigned short* qp = q + vbase + (size_t)qrow * 64 + quad * 8;
    qf0 = *(const bf16x8*)qp;
    qf1 = *(const bf16x8*)(qp + 32);
  }
  bf16x8 ones;
#pragma unroll
  for (int z = 0; z < 8; ++z) ones[z] = (short)0x3F80;   // 1.0 bf16

  floatx4 accO[4] = {};   // O[q=quad*4+i][d=dt*16+m16]
  floatx4 accL = {};      // l[q=quad*4+i]
  float mrow = -1e30f;    // per-lane running max, query = m16

  for (int kt = 0; kt < 16; ++kt) {
    int kb = ks * 16 + kt;                 // 128-key block index
    __syncthreads();
#pragma unroll
    for (int pp = 0; pp < 4; ++pp) {
      int f = (pp * 256 + tid) * 8;
      int rv = f >> 7, cv = f & 127;      // V: 64 rows x 128 keys
      *(uint4*)&Vt[rv][cv] = *(const uint4*)(vt + vbase + (size_t)rv * 4096 + key0 + kt * 128 + cv);
    }
    __syncthreads();
    // S^T = K * Q^T, K A-frags straight from Kp (permuted-key semantics:
    // s[ig][i] = S[q=m16][key = kb*128 + (ig>>1)*32 + quad*8 + (ig&1)*4 + i])
    const unsigned short* kpb = Kp + (((size_t)bh * 32 + kb) * 8) * 1024 + l * 8;
    floatx4 s[8];
#pragma unroll
    for (int ig = 0; ig < 8; ++ig) {
      bf16x8 kf0 = *(const bf16x8*)(kpb + ig * 1024);
      bf16x8 kf1 = *(const bf16x8*)(kpb + ig * 1024 + 512);
      floatx4 z = {};
      z = __builtin_amdgcn_mfma_f32_16x16x32_bf16(kf0, qf0, z, 0, 0, 0);
      s[ig] = __builtin_amdgcn_mfma_f32_16x16x32_bf16(kf1, qf1, z, 0, 0, 0);
    }
    // online softmax: reduce across quads only (xor 16, 32)
    float mx = s[0][0];
#pragma unroll
    for (int ig = 0; ig < 8; ++ig)
#pragma unroll
      for (int i = 0; i < 4; ++i) mx = fmaxf(mx, s[ig][i]);
    mx = fmaxf(mx, __shfl_xor(mx, 16));
    mx = fmaxf(mx, __shfl_xor(mx, 32));
    bool grew = mx > mrow;
    float mnew = fmaxf(mrow, mx);
#pragma unroll
    for (int ig = 0; ig < 8; ++ig)
#pragma unroll
      for (int i = 0; i < 4; ++i)
        s[ig][i] = fast_exp2(s[ig][i] - mnew);
    if (__ballot(grew)) {
      float alpha = fast_exp2(mrow - mnew);
      float al0 = __shfl(alpha, quad * 4 + 0);
      float al1 = __shfl(alpha, quad * 4 + 1);
      float al2 = __shfl(alpha, quad * 4 + 2);
      float al3 = __shfl(alpha, quad * 4 + 3);
#pragma unroll
      for (int dt = 0; dt < 4; ++dt) {
        accO[dt][0] *= al0; accO[dt][1] *= al1;
        accO[dt][2] *= al2; accO[dt][3] *= al3;
      }
      accL[0] *= al0; accL[1] *= al1; accL[2] *= al2; accL[3] *= al3;
    }
    mrow = mnew;
    // P -> bf16 A-frags (K=32): element j = hh*4+i from s[nt*2+hh][i]
    bf16x8 pf[4];
#pragma unroll
    for (int nt = 0; nt < 4; ++nt) {
      union { unsigned u[4]; bf16x8 v; } pu;
      pu.u[0] = pack_bf16_trunc(s[nt * 2][0],     s[nt * 2][1]);
      pu.u[1] = pack_bf16_trunc(s[nt * 2][2],     s[nt * 2][3]);
      pu.u[2] = pack_bf16_trunc(s[nt * 2 + 1][0], s[nt * 2 + 1][1]);
      pu.u[3] = pack_bf16_trunc(s[nt * 2 + 1][2], s[nt * 2 + 1][3]);
      pf[nt] = pu.v;
    }
    // O += P*V (K=32): B-frag = Vt[d=dt*16+m16][key = nt*32+quad*8..+7], b128
#pragma unroll
    for (int dt = 0; dt < 4; ++dt) {
#pragma unroll
      for (int nt = 0; nt < 4; ++nt) {
        bf16x8 vf = *(const bf16x8*)&Vt[dt * 16 + m16][nt * 32 + quad * 8];
        accO[dt] = __builtin_amdgcn_mfma_f32_16x16x32_bf16(pf[nt], vf, accO[dt], 0, 0, 0);
      }
    }
#pragma unroll
    for (int nt = 0; nt < 4; ++nt)
      accL = __builtin_amdgcn_mfma_f32_16x16x32_bf16(pf[nt], ones, accL, 0, 0, 0);
  }
  // ---- epilogue: normalized bf16 partial O + (m,l) per query ----
  const size_t prow = (size_t)(ks * 16 + bh) * 4096;
  float li0 = 1.f / accL[0];
  float li1 = 1.f / accL[1];
  float li2 = 1.f / accL[2];
  float li3 = 1.f / accL[3];
#pragma unroll
  for (int dt = 0; dt < 4; ++dt) {
    int d = dt * 16 + m16;
    int qrow = qt * 64 + w * 16 + quad * 4;
    size_t rb = (prow + qrow) * 64 + d;
    pO[rb]       = f2b(accO[dt][0] * li0);
    pO[rb + 64]  = f2b(accO[dt][1] * li1);
    pO[rb + 128] = f2b(accO[dt][2] * li2);
    pO[rb + 192] = f2b(accO[dt][3] * li3);
  }
  if (m16 < 4) {
    float mv = __shfl(mrow, quad * 4 + m16);
    float lv = (m16 == 0) ? accL[0] : (m16 == 1) ? accL[1] : (m16 == 2) ? accL[2] : accL[3];
    int qrow = qt * 64 + w * 16 + quad * 4 + m16;
    float2 v; v.x = mv; v.y = lv;
    ((float2*)mlbuf)[prow + qrow] = v;
  }
}

// ---------------- 5b. LSE merge of the two kv-splits ----------------
__global__ __launch_bounds__(256) void attn_merge(
    const unsigned short* __restrict__ pO, const float* __restrict__ mlbuf,
    unsigned short* __restrict__ ob) {
  int r = blockIdx.x * 64 + (threadIdx.x >> 2);   // row over 16 bh x 4096 q
  int dseg = (threadIdx.x & 3) * 16;
  int bh = r >> 12, qq = r & 4095;
  int b = bh >> 3, h = bh & 7;
  const float2* mlp = (const float2*)mlbuf;
  float2 ml0 = mlp[r];
  float2 ml1 = mlp[65536 + r];
  float ms = fmaxf(ml0.x, ml1.x);
  float s0 = fast_exp2(ml0.x - ms) * ml0.y;
  float s1 = fast_exp2(ml1.x - ms) * ml1.y;
  float inv = 1.f / (s0 + s1);
  float w0 = s0 * inv, w1 = s1 * inv;
  const unsigned short* p0 = pO + ((size_t)r * 64 + dseg);
  const unsigned short* p1 = p0 + (size_t)65536 * 64;
  uint4 u0a = *(const uint4*)p0, u0b = *(const uint4*)(p0 + 8);
  uint4 u1a = *(const uint4*)p1, u1b = *(const uint4*)(p1 + 8);
  const unsigned short* a0 = (const unsigned short*)&u0a;
  const unsigned short* a1 = (const unsigned short*)&u1a;
  const unsigned short* b0p = (const unsigned short*)&u0b;
  const unsigned short* b1p = (const unsigned short*)&u1b;
  unsigned short u[16];
#pragma unroll
  for (int z = 0; z < 8; ++z) {
    u[z]     = f2b(w0 * b2f(a0[z])  + w1 * b2f(a1[z]));
    u[8 + z] = f2b(w0 * b2f(b0p[z]) + w1 * b2f(b1p[z]));
  }
  unsigned short* op = ob + ((size_t)(b * 4096 + qq)) * 512 + h * 64 + dseg;
  *(uint4*)op       = *(uint4*)u;
  *(uint4*)(op + 8) = *(uint4*)(u + 8);
}

// ---------------- 6. out-proj + bias + residual, coalesced fp32 store ----------------
__global__ __launch_bounds__(256) void gemm_out(
    const unsigned short* __restrict__ o, const unsigned short* __restrict__ Wp,
    const float* __restrict__ bp, const float* __restrict__ x,
    float* __restrict__ out) {
  int C0 = blockIdx.x * 64, P0 = blockIdx.y * 64, b = blockIdx.z;
  __shared__ unsigned short At[64][72];   // Wp rows (channel)
  __shared__ unsigned short Bt[64][72];   // o rows (pixel)
  int tid = threadIdx.x, w = tid >> 6, l = tid & 63;
  int quad = l >> 4, m16 = l & 15;
  floatx4 acc[4] = {};
  for (int k0 = 0; k0 < 512; k0 += 64) {
    __syncthreads();
#pragma unroll
    for (int pp = 0; pp < 2; ++pp) {
      int f = (pp * 256 + tid) * 8;
      int r = f >> 6, c = f & 63;
      *(uint4*)&At[r][c] = *(const uint4*)(Wp + (size_t)(C0 + r) * 512 + k0 + c);
      *(uint4*)&Bt[r][c] = *(const uint4*)(o + ((size_t)(b * 4096 + P0 + r)) * 512 + k0 + c);
    }
    __syncthreads();
    bf16x8 af0 = *(const bf16x8*)&At[w * 16 + m16][quad * 8];
    bf16x8 af1 = *(const bf16x8*)&At[w * 16 + m16][32 + quad * 8];
#pragma unroll
    for (int nt = 0; nt < 4; ++nt) {
      bf16x8 b0 = *(const bf16x8*)&Bt[nt * 16 + m16][quad * 8];
      bf16x8 b1 = *(const bf16x8*)&Bt[nt * 16 + m16][32 + quad * 8];
      acc[nt] = __builtin_amdgcn_mfma_f32_16x16x32_bf16(af0, b0, acc[nt], 0, 0, 0);
      acc[nt] = __builtin_amdgcn_mfma_f32_16x16x32_bf16(af1, b1, acc[nt], 0, 0, 0);
    }
  }
#pragma unroll
  for (int r = 0; r < 4; ++r) {
    int c = C0 + w * 16 + quad * 4 + r;
    float bias = bp[c];
#pragma unroll
    for (int nt = 0; nt < 4; ++nt) {
      int p = P0 + nt * 16 + m16;
      size_t idx = ((size_t)(b * 512 + c)) * 4096 + p;
      out[idx] = acc[nt][r] + bias + x[idx];
    }
  }
}

extern "C" void kernel_launch(void* const* d_in, const int* in_sizes, int n_in,
                              void* d_out, int out_size, void* d_ws, size_t ws_size,
                              hipStream_t stream) {
  const float* x   = (const float*)d_in[0];
  const float* gnw = (const float*)d_in[1];
  const float* gnb = (const float*)d_in[2];
  const float* wq  = (const float*)d_in[3];
  const float* bq  = (const float*)d_in[4];
  const float* wk  = (const float*)d_in[5];
  const float* bk  = (const float*)d_in[6];
  const float* wv  = (const float*)d_in[7];
  const float* bv  = (const float*)d_in[8];
  const float* wp  = (const float*)d_in[9];
  const float* bp  = (const float*)d_in[10];
  float* out = (float*)d_out;

  char* ws = (char*)d_ws;
  float* stat          = (float*)ws;          ws += 1024;
  float* bqkv          = (float*)ws;          ws += 8192;
  unsigned short* Wqkv = (unsigned short*)ws; ws += (size_t)1536 * 512 * 2;
  unsigned short* Wp   = (unsigned short*)ws; ws += (size_t)512 * 512 * 2;
  unsigned short* t    = (unsigned short*)ws; ws += (size_t)8192 * 512 * 2;
  unsigned short* qb   = (unsigned short*)ws; ws += (size_t)8192 * 512 * 2;
  unsigned short* Kp   = (unsigned short*)ws; ws += (size_t)8192 * 512 * 2;  // frag-major K
  unsigned short* vb   = (unsigned short*)ws; ws += (size_t)8192 * 512 * 2;  // [16][64][4096]
  unsigned short* ob   = (unsigned short*)ws; ws += (size_t)8192 * 512 * 2;

  // attn partials: d_out (16.78 MB, exactly 2x16x4096x64 bf16; fully
  // overwritten by gemm_out). (m,l) stats: reuse t (dead after gemm_qkv).
  unsigned short* pO  = (unsigned short*)d_out;
  float* mlbuf        = (float*)t;

  hipMemsetAsync(stat, 0, 512, stream);
  dim3 g0(64, 8);
  gn_stats<<<g0, 256, 0, stream>>>(x, stat);
  prep_w<<<4103, 256, 0, stream>>>(wq, wk, wv, wp, bq, bk, bv, Wqkv, Wp, bqkv);
  gn_apply<<<1024, 256, 0, stream>>>(x, stat, gnw, gnb, t);
  dim3 g1(128, 24);
  gemm_qkv<<<g1, 256, 0, stream>>>(t, Wqkv, bqkv, qb, Kp, vb);
  dim3 g2(64, 16, 2);
  attn<<<g2, 256, 0, stream>>>(qb, Kp, vb, pO, mlbuf);
  attn_merge<<<1024, 256, 0, stream>>>(pO, mlbuf, ob);
  dim3 g3(8, 64, 2);
  gemm_out<<<g3, 256, 0, stream>>>(ob, Wp, bp, x, out);
}